// Round 13
// baseline (1081.999 us; speedup 1.0000x reference)
//
#include <hip/hip_runtime.h>
#include <hip/hip_bf16.h>
#include <hip/hip_fp8.h>

typedef __attribute__((ext_vector_type(4))) float f32x4;
typedef __attribute__((ext_vector_type(2))) long long ll2;

#define AS1 __attribute__((address_space(1)))
#define AS3 __attribute__((address_space(3)))

static constexpr int Mdim = 4096;
static constexpr int Kdim = 7168;
static constexpr int Ndim = 16384;
static constexpr int KB   = Kdim / 128;   // 56 scale blocks
static constexpr float FP8_MAX = 448.0f;

// compiler-fence + raw barrier (no implicit vmcnt(0) drain)
#define BARRIER() do { asm volatile("" ::: "memory"); \
                       __builtin_amdgcn_s_barrier();  \
                       asm volatile("" ::: "memory"); } while (0)

#define MFMA_FP8 __builtin_amdgcn_mfma_f32_16x16x32_fp8_fp8

// ---------------------------------------------------------------------------
// Kernel 1: activation quant  x[M,K] f32 -> xq[M,K] fp8  +  xs_t[KB][M] f32
// ---------------------------------------------------------------------------
__global__ __launch_bounds__(256) void quant_x_kernel(
    const float* __restrict__ x, unsigned char* __restrict__ xq,
    float* __restrict__ xst)
{
    constexpr int NBLK = Mdim * KB;
    const int lane = threadIdx.x & 63;
    const int wid  = (blockIdx.x * 256 + threadIdx.x) >> 6;
    const int nw   = (gridDim.x * 256) >> 6;

    for (int b = wid; b < NBLK; b += nw) {
        size_t base = (size_t)b * 128 + lane * 2;
        float2 v = *reinterpret_cast<const float2*>(x + base);
        float amax = fmaxf(fabsf(v.x), fabsf(v.y));
#pragma unroll
        for (int off = 32; off > 0; off >>= 1)
            amax = fmaxf(amax, __shfl_xor(amax, off));
        float s = amax * (1.0f / FP8_MAX);
        unsigned char q0 = 0, q1 = 0;
        if (s > 0.0f) {
            q0 = __hip_fp8_e4m3(v.x / s).__x;
            q1 = __hip_fp8_e4m3(v.y / s).__x;
        }
        *reinterpret_cast<unsigned short*>(xq + base) =
            (unsigned short)(q0 | ((unsigned short)q1 << 8));
        if (lane == 0) {
            int row = b / KB, kb = b - row * KB;
            xst[(size_t)kb * Mdim + row] = s;
        }
    }
}

// ---------------------------------------------------------------------------
// Kernel 2: weight quant  w[N,K] f32 -> w8[N,K] fp8 (plain RNE cast)
// ---------------------------------------------------------------------------
__global__ __launch_bounds__(256) void quant_w_kernel(
    const float* __restrict__ w, unsigned char* __restrict__ w8)
{
    constexpr size_t NCHUNK = (size_t)Ndim * Kdim / 8;

    size_t idx    = (size_t)blockIdx.x * 256 + threadIdx.x;
    size_t stride = (size_t)gridDim.x * 256;

    for (size_t c = idx; c < NCHUNK; c += stride) {
        const float* src = w + c * 8;
        float4 v0 = *reinterpret_cast<const float4*>(src);
        float4 v1 = *reinterpret_cast<const float4*>(src + 4);
        unsigned int lo = (unsigned int)__hip_fp8_e4m3(v0.x).__x
                        | ((unsigned int)__hip_fp8_e4m3(v0.y).__x << 8)
                        | ((unsigned int)__hip_fp8_e4m3(v0.z).__x << 16)
                        | ((unsigned int)__hip_fp8_e4m3(v0.w).__x << 24);
        unsigned int hi = (unsigned int)__hip_fp8_e4m3(v1.x).__x
                        | ((unsigned int)__hip_fp8_e4m3(v1.y).__x << 8)
                        | ((unsigned int)__hip_fp8_e4m3(v1.z).__x << 16)
                        | ((unsigned int)__hip_fp8_e4m3(v1.w).__x << 24);
        uint2 p; p.x = lo; p.y = hi;
        *reinterpret_cast<uint2*>(w8 + c * 8) = p;
    }
}

// ---------------------------------------------------------------------------
// Kernel 3: 256x128 NT GEMM, fp8-resident, 8 waves (4M x 2N), per-wave
// 64x64 -> acc[4][4]=64 f32/lane.  Combines the two verified constraints:
//   - spill-free: 512-thr WG + acc=64 (round 11: VGPR 84, WRITE == C)
//   - low fetch:  BM=256 -> 16 tile-rows, 2 tile-rows/XCD (~1.07 GB,
//     rounds 8/10/12)
//
// LDS map (106720 B):
//   [0,49152):        2 buf x { A[256 rows][64 B] @0, B[128 rows][64 B] @16384 }
//   [49152,106496):   xs slice [56 kb][256 rows] f32 (rows bm..bm+256)
//   [106496,106720):  ws slice [56 kb] f32 (single nb block, BN=128)
//
// b128 k-permutation reads (verified 0-conflict, rounds 9-12): lane reads
// 16 B at phys slot lk ^ ((lr>>1)&3); MFMA call 0 = lo 8 B, call 1 = hi
// 8 B; same permutation on A and B => exact dot product.  Staging source
// uses the same involution; LDS dest linear (wave-uniform base + lane*16).
//
// Stage calls (T, r): r 0:A-rows-0-127, 1:A-rows-128-255, 2:B.
// regByte = (T&1)*24576 + r*8192; one 16B load/thread/call (8 KB region).
// Per tile t (buf = t&1):
//   W1: stage(t+1,0); stage(t+1,1) @buf^1; read a(4xb128), b0,b1(4xb128);
//       sv from LDS; Q0 = 4m x {n0,n1}; lgkmcnt(0); BARRIER
//   W2: stage(t+2,2) @buf; Q1 = 4m x {n2,n3} (register-only);
//       vmcnt(1) [t<NT-2] else vmcnt(0); BARRIER
// Residency: outstanding after W2 = {A0(t+1), A1(t+1), B(t+2)}; vmcnt(1)
// waits both A halves of t+1 (B(t+1) issued one tile earlier -> done).
// Overwrite safety: W1 writes A@buf^1 (reads a@buf); W2 writes B@buf for
// t+2 with all tile-t B-reads drained by W1's lgkmcnt(0) before the
// W1->W2 barrier.  Prologue: xs(7 calls) + ws(wave0) + A0,A1,B(0) + B(1);
// vmcnt(1) leaves only B(1) in flight -> scales + tile0 resident.
// ---------------------------------------------------------------------------
constexpr int BM = 256, BN = 128, BK = 64;
constexpr int NT  = Kdim / BK;            // 112 K-tiles
constexpr int NBN = Ndim / BN;            // 128
constexpr int NWG = (Mdim / BM) * NBN;    // 2048 (%8 == 0)
constexpr int K1  = Kdim;                 // fp8 row stride in bytes
constexpr int BUFSZ  = 24576;
constexpr int XS_OFF = 49152;
constexpr int WS_OFF = XS_OFF + 56 * 1024;       // 106496
constexpr int LDS_TOT = WS_OFF + 224;            // 106720

__global__ __launch_bounds__(512, 2) void gemm_fp8_kernel(
    const unsigned char* __restrict__ Ag,   // xq  [M][K] fp8
    const unsigned char* __restrict__ Bg,   // w8  [N][K] fp8
    const float* __restrict__ xsT,          // [KB][M] f32
    const float* __restrict__ Wsc,          // [N/128][KB] f32
    float* __restrict__ C)
{
    extern __shared__ char smem[];   // LDS_TOT bytes

    const int tid  = threadIdx.x;
    const int w    = tid >> 6;        // 0..7
    const int lane = tid & 63;
    const int wr   = w >> 1;          // 0..3 (M)
    const int wc   = w & 1;           // 0..1 (N)
    const int lr   = lane & 15;
    const int lk   = lane >> 4;

    // XCD-bijective block swizzle (2 tile-rows per XCD)
    int bid = (int)blockIdx.x;
    int swz = (bid & 7) * (NWG >> 3) + (bid >> 3);
    const int bm = (swz / NBN) * BM;
    const int bn = (swz % NBN) * BN;

    // swizzled b128 read column (bytes within a 64-B row); lane-constant
    const int colF = (lk ^ ((lr >> 1) & 3)) << 4;
    const int aRow = wr * 64;         // wave's row base in A region (0..255)
    const int bRow = wc * 64;         // wave's row base in B region (0..127)

    // LDS scale bases
    const char* xsL0 = smem + XS_OFF + (wr * 64 + lk * 4) * 4;
    const char* wsL  = smem + WS_OFF;

    // staging: 1 chunk (16B) per thread per call (involution matches read)
    const int rowS = tid >> 2;                            // 0..127
    const int colS = (((tid & 3) ^ ((rowS >> 1) & 3))) * 16;
    const size_t offG = (size_t)rowS * K1 + colS;
    const int ldsW = w * 1024;        // wave-uniform; HW adds lane*16

    const char* Ab = (const char*)Ag + (size_t)bm * K1;
    const char* Bb = (const char*)Bg + (size_t)bn * K1;

    auto stage = [&](int T, int r) {   // r: 0=A rows 0-127, 1=A rows 128-255, 2=B
        if (T >= NT) return;
        const int regByte = (T & 1) * BUFSZ + r * 8192;
        const char* g = (r == 2 ? Bb : Ab + (size_t)r * (128 * (size_t)K1))
                        + (size_t)T * 64 + offG;
        __builtin_amdgcn_global_load_lds((const AS1 void*)g,
                                         (AS3 void*)(smem + regByte + ldsW),
                                         16, 0, 0);
    };

    // ---- prologue: scales (7 xs calls + ws), tile0 {A0,A1,B}, tile1 {B} ----
#pragma unroll
    for (int i = 0; i < 7; ++i) {
        const int kb = i * 8 + w;                     // 0..55, wave-uniform
        const float* g = xsT + (size_t)kb * Mdim + bm + lane * 4;
        __builtin_amdgcn_global_load_lds((const AS1 void*)g,
            (AS3 void*)(smem + XS_OFF + i * 8192 + ldsW), 16, 0, 0);
    }
    if (w == 0 && lane < 14) {
        const float* g = Wsc + (size_t)(bn >> 7) * KB + lane * 4;
        __builtin_amdgcn_global_load_lds((const AS1 void*)g,
            (AS3 void*)(smem + WS_OFF), 16, 0, 0);
    }
    stage(0, 0); stage(0, 1); stage(0, 2);
    stage(1, 2);
    asm volatile("s_waitcnt vmcnt(1)" ::: "memory");  // scales + tile0 resident
    BARRIER();

    f32x4 acc[4][4] = {};

    for (int t = 0; t < NT; ++t) {
        const int buf = t & 1;
        const int kb  = t >> 1;
        const char* aB = smem + buf * BUFSZ;
        const char* bB = smem + buf * BUFSZ + 16384;
        ll2 a[4], b0[2], b1[2];
        f32x4 sv[4];

        const float wsv  = *(const float*)(wsL + kb * 4);
        const char* xsLk = xsL0 + (kb << 10);

        // ================= W1 : Q0 (n0,n1) =================
        stage(t + 1, 0);                       // A0(t+1) @ buf^1
        stage(t + 1, 1);                       // A1(t+1) @ buf^1
#pragma unroll
        for (int m = 0; m < 4; ++m)
            a[m] = *(const ll2*)(aB + (aRow + m * 16 + lr) * 64 + colF);
#pragma unroll
        for (int n = 0; n < 2; ++n)
            b0[n] = *(const ll2*)(bB + (bRow + n * 16 + lr) * 64 + colF);
#pragma unroll
        for (int n = 0; n < 2; ++n)
            b1[n] = *(const ll2*)(bB + (bRow + (n + 2) * 16 + lr) * 64 + colF);
#pragma unroll
        for (int m = 0; m < 4; ++m)
            sv[m] = *reinterpret_cast<const f32x4*>(xsLk + m * 64) * wsv;
        __builtin_amdgcn_s_setprio(1);
#pragma unroll
        for (int m = 0; m < 4; ++m)
#pragma unroll
            for (int n = 0; n < 2; ++n) {
                f32x4 pacc = {0.f, 0.f, 0.f, 0.f};
                pacc = MFMA_FP8(a[m][0], b0[n][0], pacc, 0, 0, 0);
                pacc = MFMA_FP8(a[m][1], b0[n][1], pacc, 0, 0, 0);
                acc[m][n] += sv[m] * pacc;
            }
        __builtin_amdgcn_s_setprio(0);
        asm volatile("s_waitcnt lgkmcnt(0)" ::: "memory");  // B reads retired
        BARRIER();   // W1 -> W2

        // ================= W2 : Q1 (n2,n3) =================
        stage(t + 2, 2);                       // B(t+2) @ buf
        __builtin_amdgcn_s_setprio(1);
#pragma unroll
        for (int m = 0; m < 4; ++m)
#pragma unroll
            for (int n = 0; n < 2; ++n) {
                f32x4 pacc = {0.f, 0.f, 0.f, 0.f};
                pacc = MFMA_FP8(a[m][0], b1[n][0], pacc, 0, 0, 0);
                pacc = MFMA_FP8(a[m][1], b1[n][1], pacc, 0, 0, 0);
                acc[m][n + 2] += sv[m] * pacc;
            }
        __builtin_amdgcn_s_setprio(0);
        if (t < NT - 2) { asm volatile("s_waitcnt vmcnt(1)" ::: "memory"); }
        else            { asm volatile("s_waitcnt vmcnt(0)" ::: "memory"); }
        BARRIER();   // tile boundary: tile t+1 fully resident
    }

    // ---- epilogue: C/D layout col = lr, row = lk*4 + j ----
#pragma unroll
    for (int m = 0; m < 4; ++m) {
#pragma unroll
        for (int n = 0; n < 4; ++n) {
            const int row0 = bm + wr * 64 + m * 16 + lk * 4;
            const int col  = bn + wc * 64 + n * 16 + lr;
#pragma unroll
            for (int j = 0; j < 4; ++j)
                C[(size_t)(row0 + j) * Ndim + col] = acc[m][n][j];
        }
    }
}

// ---------------------------------------------------------------------------
extern "C" void kernel_launch(void* const* d_in, const int* in_sizes, int n_in,
                              void* d_out, int out_size, void* d_ws, size_t ws_size,
                              hipStream_t stream) {
    const float* x  = (const float*)d_in[0];
    const float* w  = (const float*)d_in[1];
    const float* ws = (const float*)d_in[2];

    unsigned char* xq  = (unsigned char*)d_ws;                       // 29.4 MB
    unsigned char* w8  = xq + (size_t)Mdim * Kdim;                   // 117.4 MB
    float*         xst = (float*)(w8 + (size_t)Ndim * Kdim);         // 0.92 MB

    quant_x_kernel<<<2048, 256, 0, stream>>>(x, xq, xst);
    quant_w_kernel<<<4096, 256, 0, stream>>>(w, w8);

    hipFuncSetAttribute((const void*)gemm_fp8_kernel,
                        hipFuncAttributeMaxDynamicSharedMemorySize, LDS_TOT);
    gemm_fp8_kernel<<<NWG, 512, LDS_TOT, stream>>>(xq, w8, xst, ws,
                                                   (float*)d_out);
}

// Round 14
// 975.045 us; speedup vs baseline: 1.1097x; 1.1097x over previous
//
#include <hip/hip_runtime.h>
#include <hip/hip_bf16.h>
#include <hip/hip_fp8.h>

typedef __attribute__((ext_vector_type(4))) float f32x4;
typedef __attribute__((ext_vector_type(2))) long long ll2;
typedef __attribute__((ext_vector_type(4))) unsigned short u16x4;

#define AS1 __attribute__((address_space(1)))
#define AS3 __attribute__((address_space(3)))

static constexpr int Mdim = 4096;
static constexpr int Kdim = 7168;
static constexpr int Ndim = 16384;
static constexpr int KB   = Kdim / 128;   // 56 scale blocks
static constexpr float FP8_MAX = 448.0f;

// compiler-fence + raw barrier (no implicit vmcnt(0) drain)
#define BARRIER() do { asm volatile("" ::: "memory"); \
                       __builtin_amdgcn_s_barrier();  \
                       asm volatile("" ::: "memory"); } while (0)

#define MFMA_FP8 __builtin_amdgcn_mfma_f32_16x16x32_fp8_fp8

// ---------------------------------------------------------------------------
// Kernel 1: activation quant  x[M,K] f32 -> xq[M,K] fp8  +  xs_t[KB][M] bf16
// ---------------------------------------------------------------------------
__global__ __launch_bounds__(256) void quant_x_kernel(
    const float* __restrict__ x, unsigned char* __restrict__ xq,
    __hip_bfloat16* __restrict__ xst)
{
    constexpr int NBLK = Mdim * KB;
    const int lane = threadIdx.x & 63;
    const int wid  = (blockIdx.x * 256 + threadIdx.x) >> 6;
    const int nw   = (gridDim.x * 256) >> 6;

    for (int b = wid; b < NBLK; b += nw) {
        size_t base = (size_t)b * 128 + lane * 2;
        float2 v = *reinterpret_cast<const float2*>(x + base);
        float amax = fmaxf(fabsf(v.x), fabsf(v.y));
#pragma unroll
        for (int off = 32; off > 0; off >>= 1)
            amax = fmaxf(amax, __shfl_xor(amax, off));
        float s = amax * (1.0f / FP8_MAX);
        unsigned char q0 = 0, q1 = 0;
        if (s > 0.0f) {
            q0 = __hip_fp8_e4m3(v.x / s).__x;
            q1 = __hip_fp8_e4m3(v.y / s).__x;
        }
        *reinterpret_cast<unsigned short*>(xq + base) =
            (unsigned short)(q0 | ((unsigned short)q1 << 8));
        if (lane == 0) {
            int row = b / KB, kb = b - row * KB;
            xst[(size_t)kb * Mdim + row] = __float2bfloat16(s);
        }
    }
}

// ---------------------------------------------------------------------------
// Kernel 2: weight quant  w[N,K] f32 -> w8[N,K] fp8 (plain RNE cast)
// ---------------------------------------------------------------------------
__global__ __launch_bounds__(256) void quant_w_kernel(
    const float* __restrict__ w, unsigned char* __restrict__ w8)
{
    constexpr size_t NCHUNK = (size_t)Ndim * Kdim / 8;

    size_t idx    = (size_t)blockIdx.x * 256 + threadIdx.x;
    size_t stride = (size_t)gridDim.x * 256;

    for (size_t c = idx; c < NCHUNK; c += stride) {
        const float* src = w + c * 8;
        float4 v0 = *reinterpret_cast<const float4*>(src);
        float4 v1 = *reinterpret_cast<const float4*>(src + 4);
        unsigned int lo = (unsigned int)__hip_fp8_e4m3(v0.x).__x
                        | ((unsigned int)__hip_fp8_e4m3(v0.y).__x << 8)
                        | ((unsigned int)__hip_fp8_e4m3(v0.z).__x << 16)
                        | ((unsigned int)__hip_fp8_e4m3(v0.w).__x << 24);
        unsigned int hi = (unsigned int)__hip_fp8_e4m3(v1.x).__x
                        | ((unsigned int)__hip_fp8_e4m3(v1.y).__x << 8)
                        | ((unsigned int)__hip_fp8_e4m3(v1.z).__x << 16)
                        | ((unsigned int)__hip_fp8_e4m3(v1.w).__x << 24);
        uint2 p; p.x = lo; p.y = hi;
        *reinterpret_cast<uint2*>(w8 + c * 8) = p;
    }
}

// ---------------------------------------------------------------------------
// Kernel 3: 256x128 NT GEMM, fp8-resident — round-13 kernel (spill-free,
// ideal fetch, 0 conflicts) with ONE structural change: xs scales stored
// bf16 in LDS -> per-WG LDS 78.0 KB -> TWO WGs per CU (4 waves/SIMD).
// Round-13 diagnosis: all pathologies fixed but 1 WG/CU barrier-lockstep
// left ~55% of SIMD cycles dead; cross-WG TLP is the missing overlap.
//
// LDS map (78048 B):
//   [0,49152):       2 buf x { A[256 rows][64 B] @0, B[128 rows][64 B] @16384 }
//   [49152,77824):   xs slice [56 kb][256 rows] bf16 (rows bm..bm+256)
//   [77824,78048):   ws slice [56 kb] f32 (single nb block, BN=128)
//
// b128 k-permutation reads (verified 0-conflict): lane reads 16 B at phys
// slot lk ^ ((lr>>1)&3); MFMA call 0 = lo 8 B, call 1 = hi 8 B; same
// permutation on A and B => exact dot product. Staging involution matches.
//
// Protocol per tile t (buf = t&1)  [round-13 verified]:
//   W1: stage(t+1,A0); stage(t+1,A1) @buf^1; read a,b0,b1; sv from LDS
//       (b64 broadcast + shl-16 bf16->f32); Q0; lgkmcnt(0); BARRIER
//   W2: stage(t+2,B) @buf; Q1 (register-only);
//       vmcnt(1) [t<NT-2] else vmcnt(0); BARRIER
// Residency: outstanding after W2 = {A0(t+1), A1(t+1), B(t+2)} -> vmcnt(1)
// waits both A halves of t+1. Overwrite safety: W1 writes A@buf^1 (reads
// @buf); W2 writes B@buf for t+2 after W1's lgkmcnt(0) drained tile-t
// B-reads. Prologue vmcnt(1): only newest call (tile1 B) in flight.
// __launch_bounds__(512,4): 4 waves/EU -> 2 WGs/CU, VGPR cap 128 (use ~84).
// ---------------------------------------------------------------------------
constexpr int BM = 256, BN = 128, BK = 64;
constexpr int NT  = Kdim / BK;            // 112 K-tiles
constexpr int NBN = Ndim / BN;            // 128
constexpr int NWG = (Mdim / BM) * NBN;    // 2048 (%8 == 0)
constexpr int K1  = Kdim;                 // fp8 row stride in bytes
constexpr int BUFSZ  = 24576;
constexpr int XS_OFF = 49152;
constexpr int WS_OFF = XS_OFF + 56 * 512;        // 77824 (xs bf16: 28672 B)
constexpr int LDS_TOT = WS_OFF + 224;            // 78048

__global__ __launch_bounds__(512, 4) void gemm_fp8_kernel(
    const unsigned char* __restrict__ Ag,   // xq  [M][K] fp8
    const unsigned char* __restrict__ Bg,   // w8  [N][K] fp8
    const __hip_bfloat16* __restrict__ xsT, // [KB][M] bf16
    const float* __restrict__ Wsc,          // [N/128][KB] f32
    float* __restrict__ C)
{
    extern __shared__ char smem[];   // LDS_TOT bytes

    const int tid  = threadIdx.x;
    const int w    = tid >> 6;        // 0..7
    const int lane = tid & 63;
    const int wr   = w >> 1;          // 0..3 (M)
    const int wc   = w & 1;           // 0..1 (N)
    const int lr   = lane & 15;
    const int lk   = lane >> 4;

    // XCD-bijective block swizzle (2 tile-rows per XCD)
    int bid = (int)blockIdx.x;
    int swz = (bid & 7) * (NWG >> 3) + (bid >> 3);
    const int bm = (swz / NBN) * BM;
    const int bn = (swz % NBN) * BN;

    // swizzled b128 read column (bytes within a 64-B row); lane-constant
    const int colF = (lk ^ ((lr >> 1) & 3)) << 4;
    const int aRow = wr * 64;         // wave's row base in A region (0..255)
    const int bRow = wc * 64;         // wave's row base in B region (0..127)

    // LDS scale bases (bf16 xs: row stride 2 B, kb stride 512 B)
    const char* xsL0 = smem + XS_OFF + (wr * 64 + lk * 4) * 2;
    const char* wsL  = smem + WS_OFF;

    // staging: 1 chunk (16B) per thread per call (involution matches read)
    const int rowS = tid >> 2;                            // 0..127
    const int colS = (((tid & 3) ^ ((rowS >> 1) & 3))) * 16;
    const size_t offG = (size_t)rowS * K1 + colS;
    const int ldsW = w * 1024;        // wave-uniform; HW adds lane*16

    const char* Ab = (const char*)Ag + (size_t)bm * K1;
    const char* Bb = (const char*)Bg + (size_t)bn * K1;

    auto stage = [&](int T, int r) {   // r: 0=A rows 0-127, 1=A rows 128-255, 2=B
        if (T >= NT) return;
        const int regByte = (T & 1) * BUFSZ + r * 8192;
        const char* g = (r == 2 ? Bb : Ab + (size_t)r * (128 * (size_t)K1))
                        + (size_t)T * 64 + offG;
        __builtin_amdgcn_global_load_lds((const AS1 void*)g,
                                         (AS3 void*)(smem + regByte + ldsW),
                                         16, 0, 0);
    };

    // ---- prologue: xs (3.5 calls of 512x16B), ws, tile0 {A0,A1,B}, tile1 {B}
#pragma unroll
    for (int i = 0; i < 4; ++i) {
        const int c = i * 512 + tid;      // 16-B chunk; 1792 total (28 KB)
        if (i < 3 || w < 4) {             // wave-uniform guard
            const int kb  = c >> 5;       // 32 chunks per kb
            const int row = (c & 31) * 8; // 8 bf16 rows per chunk
            const __hip_bfloat16* g = xsT + (size_t)kb * Mdim + bm + row;
            __builtin_amdgcn_global_load_lds((const AS1 void*)g,
                (AS3 void*)(smem + XS_OFF + i * 8192 + ldsW), 16, 0, 0);
        }
    }
    if (w == 0 && lane < 14) {
        const float* g = Wsc + (size_t)(bn >> 7) * KB + lane * 4;
        __builtin_amdgcn_global_load_lds((const AS1 void*)g,
            (AS3 void*)(smem + WS_OFF), 16, 0, 0);
    }
    stage(0, 0); stage(0, 1); stage(0, 2);
    stage(1, 2);
    asm volatile("s_waitcnt vmcnt(1)" ::: "memory");  // scales + tile0 resident
    BARRIER();

    f32x4 acc[4][4] = {};

    for (int t = 0; t < NT; ++t) {
        const int buf = t & 1;
        const int kb  = t >> 1;
        const char* aB = smem + buf * BUFSZ;
        const char* bB = smem + buf * BUFSZ + 16384;
        ll2 a[4], b0[2], b1[2];
        f32x4 sv[4];

        const float wsv  = *(const float*)(wsL + kb * 4);
        const char* xsLk = xsL0 + kb * 512;

        // ================= W1 : Q0 (n0,n1) =================
        stage(t + 1, 0);                       // A0(t+1) @ buf^1
        stage(t + 1, 1);                       // A1(t+1) @ buf^1
#pragma unroll
        for (int m = 0; m < 4; ++m)
            a[m] = *(const ll2*)(aB + (aRow + m * 16 + lr) * 64 + colF);
#pragma unroll
        for (int n = 0; n < 2; ++n)
            b0[n] = *(const ll2*)(bB + (bRow + n * 16 + lr) * 64 + colF);
#pragma unroll
        for (int n = 0; n < 2; ++n)
            b1[n] = *(const ll2*)(bB + (bRow + (n + 2) * 16 + lr) * 64 + colF);
#pragma unroll
        for (int m = 0; m < 4; ++m) {
            u16x4 sr = *(const u16x4*)(xsLk + m * 32);   // 4 bf16 rows
            f32x4 s;
            s[0] = __uint_as_float((unsigned)sr[0] << 16);
            s[1] = __uint_as_float((unsigned)sr[1] << 16);
            s[2] = __uint_as_float((unsigned)sr[2] << 16);
            s[3] = __uint_as_float((unsigned)sr[3] << 16);
            sv[m] = s * wsv;
        }
        __builtin_amdgcn_s_setprio(1);
#pragma unroll
        for (int m = 0; m < 4; ++m)
#pragma unroll
            for (int n = 0; n < 2; ++n) {
                f32x4 pacc = {0.f, 0.f, 0.f, 0.f};
                pacc = MFMA_FP8(a[m][0], b0[n][0], pacc, 0, 0, 0);
                pacc = MFMA_FP8(a[m][1], b0[n][1], pacc, 0, 0, 0);
                acc[m][n] += sv[m] * pacc;
            }
        __builtin_amdgcn_s_setprio(0);
        asm volatile("s_waitcnt lgkmcnt(0)" ::: "memory");  // B reads retired
        BARRIER();   // W1 -> W2

        // ================= W2 : Q1 (n2,n3) =================
        stage(t + 2, 2);                       // B(t+2) @ buf
        __builtin_amdgcn_s_setprio(1);
#pragma unroll
        for (int m = 0; m < 4; ++m)
#pragma unroll
            for (int n = 0; n < 2; ++n) {
                f32x4 pacc = {0.f, 0.f, 0.f, 0.f};
                pacc = MFMA_FP8(a[m][0], b1[n][0], pacc, 0, 0, 0);
                pacc = MFMA_FP8(a[m][1], b1[n][1], pacc, 0, 0, 0);
                acc[m][n + 2] += sv[m] * pacc;
            }
        __builtin_amdgcn_s_setprio(0);
        if (t < NT - 2) { asm volatile("s_waitcnt vmcnt(1)" ::: "memory"); }
        else            { asm volatile("s_waitcnt vmcnt(0)" ::: "memory"); }
        BARRIER();   // tile boundary: tile t+1 fully resident
    }

    // ---- epilogue: C/D layout col = lr, row = lk*4 + j ----
#pragma unroll
    for (int m = 0; m < 4; ++m) {
#pragma unroll
        for (int n = 0; n < 4; ++n) {
            const int row0 = bm + wr * 64 + m * 16 + lk * 4;
            const int col  = bn + wc * 64 + n * 16 + lr;
#pragma unroll
            for (int j = 0; j < 4; ++j)
                C[(size_t)(row0 + j) * Ndim + col] = acc[m][n][j];
        }
    }
}

// ---------------------------------------------------------------------------
extern "C" void kernel_launch(void* const* d_in, const int* in_sizes, int n_in,
                              void* d_out, int out_size, void* d_ws, size_t ws_size,
                              hipStream_t stream) {
    const float* x  = (const float*)d_in[0];
    const float* w  = (const float*)d_in[1];
    const float* ws = (const float*)d_in[2];

    unsigned char*   xq  = (unsigned char*)d_ws;                     // 29.4 MB
    unsigned char*   w8  = xq + (size_t)Mdim * Kdim;                 // 117.4 MB
    __hip_bfloat16*  xst = (__hip_bfloat16*)(w8 + (size_t)Ndim * Kdim); // 0.46 MB

    quant_x_kernel<<<2048, 256, 0, stream>>>(x, xq, xst);
    quant_w_kernel<<<4096, 256, 0, stream>>>(w, w8);

    hipFuncSetAttribute((const void*)gemm_fp8_kernel,
                        hipFuncAttributeMaxDynamicSharedMemorySize, LDS_TOT);
    gemm_fp8_kernel<<<NWG, 512, LDS_TOT, stream>>>(xq, w8, xst, ws,
                                                   (float*)d_out);
}